// Round 10
// baseline (206.417 us; speedup 1.0000x reference)
//
#include <hip/hip_runtime.h>
#include <math.h>

#define NN 50000
#define EE 800000
#define ET (EE + NN)      // edges + self loops
#define F_IN 128
#define HEADS 8
#define HID 16
#define C1 (HEADS * HID)  // 128
#define CLASSES 40
#define NEG_SLOPE 0.2f
#define LOG2E 1.4426950408889634f

#define NCHUNKS ((NN + 1023) / 1024)  // 49
#define NHIST 64                      // edge partitions (hist + fill)
#define EPB (EE / NHIST)              // 12500 edges per partition
#define PADN (NCHUNKS * 1024)         // 50176 padded dst slots
#define LDSW (PADN / 4)               // 12544 u32 words of packed-u8 counters
#define GB ((NN + 63) / 64)           // 782 gemm1 blocks (64 rows each)

typedef __attribute__((ext_vector_type(8))) short bf16x8;
typedef __attribute__((ext_vector_type(4))) float f32x4;
typedef __attribute__((ext_vector_type(8))) _Float16 h16x8;
typedef __attribute__((ext_vector_type(2))) _Float16 h16x2;

__device__ __forceinline__ unsigned cvtpk(float a, float b) {
    unsigned r;
    asm("v_cvt_pk_bf16_f32 %0, %1, %2" : "=v"(r) : "v"(a), "v"(b));
    return r;
}
__device__ __forceinline__ float fexp2(float x) {
    float r;
    asm("v_exp_f32 %0, %1\n\ts_nop 0" : "=v"(r) : "v"(x));
    return r;
}
__device__ __forceinline__ float bflo(unsigned u) { return __uint_as_float(u << 16); }
__device__ __forceinline__ float bfhi(unsigned u) { return __uint_as_float(u & 0xffff0000u); }
__device__ __forceinline__ float lrelu(float a) { return fmaxf(a, NEG_SLOPE * a); }
__device__ __forceinline__ unsigned short bf1(float a) { return (unsigned short)cvtpk(a, a); }
__device__ __forceinline__ float bf1f(float a) { return bflo(cvtpk(a, a)); }
__device__ __forceinline__ bf16x8 pack8(float f0, float f1, float f2, float f3,
                                        float f4, float f5, float f6, float f7) {
    union { unsigned u[4]; bf16x8 v; } U;
    U.u[0] = cvtpk(f0, f1);
    U.u[1] = cvtpk(f2, f3);
    U.u[2] = cvtpk(f4, f5);
    U.u[3] = cvtpk(f6, f7);
    return U.v;
}

// ---------------- prep ----------------
// block 0: va1 (16x128 hi/lo bf16, frag layout) + va2 (4x128 bf16)
// block 1: W1b — W1 as bf16 MFMA fragments
// block 2: W2b — W2 fragments, cols >= CLASSES zeroed
// blocks 3..3+NHIST: LDS-histogram degree count, u8-packed; the atomicAdd return
//                    value IS each edge's within-partition rank -> rank8[] (coalesced).
__global__ void prep_kernel(const float* __restrict__ W1,
                            const float* __restrict__ as1, const float* __restrict__ ad1,
                            const float* __restrict__ W2,
                            const float* __restrict__ as2, const float* __restrict__ ad2,
                            const int* __restrict__ ei,
                            unsigned short* __restrict__ va1h, unsigned short* __restrict__ va1l,
                            unsigned short* __restrict__ va2b,
                            unsigned short* __restrict__ W1b, unsigned short* __restrict__ W2b,
                            unsigned char* __restrict__ partial8,
                            unsigned char* __restrict__ rank8) {
    const int tid = threadIdx.x;
    const int b = blockIdx.x;
    if (b >= 3) {  // -------- histogram count + rank capture, u8-packed LDS --------
        __shared__ unsigned lhist[LDSW];
        for (int i = tid; i < LDSW; i += 256) lhist[i] = 0;
        __syncthreads();
        const int hb = b - 3;
        const int* dp = ei + EE + hb * EPB;
        unsigned char* rk = rank8 + (size_t)hb * EPB;
        for (int e0 = tid * 4; e0 < EPB; e0 += 1024) {
            int4 d4 = *(const int4*)(dp + e0);
            uchar4 r;
            {
                const unsigned d = (unsigned)d4.x, sh8 = (d & 3) << 3;
                unsigned old = atomicAdd(&lhist[d >> 2], 1u << sh8);
                r.x = (unsigned char)((old >> sh8) & 0xff);
            }
            {
                const unsigned d = (unsigned)d4.y, sh8 = (d & 3) << 3;
                unsigned old = atomicAdd(&lhist[d >> 2], 1u << sh8);
                r.y = (unsigned char)((old >> sh8) & 0xff);
            }
            {
                const unsigned d = (unsigned)d4.z, sh8 = (d & 3) << 3;
                unsigned old = atomicAdd(&lhist[d >> 2], 1u << sh8);
                r.z = (unsigned char)((old >> sh8) & 0xff);
            }
            {
                const unsigned d = (unsigned)d4.w, sh8 = (d & 3) << 3;
                unsigned old = atomicAdd(&lhist[d >> 2], 1u << sh8);
                r.w = (unsigned char)((old >> sh8) & 0xff);
            }
            *(uchar4*)(rk + e0) = r;  // coalesced rank store
        }
        __syncthreads();
        unsigned* pb = (unsigned*)(partial8 + (size_t)hb * PADN);
        for (int i = tid; i < LDSW; i += 256) pb[i] = lhist[i];
        return;
    }
    if (b == 1) {  // W1b fragments: 2048 frags, 8 per thread
        for (int f = tid; f < 2048; f += 256) {
            const int lane = f & 63, kc = (f >> 6) & 3, ntw = f >> 8;
            const int q = lane >> 4, c = lane & 15;
            const int col = ntw * 16 + c;
            const int k0 = kc * 32 + q * 8;
            const float* wp = W1 + (size_t)k0 * C1 + col;
            *(bf16x8*)(W1b + (size_t)f * 8) =
                pack8(wp[0], wp[C1], wp[2 * C1], wp[3 * C1],
                      wp[4 * C1], wp[5 * C1], wp[6 * C1], wp[7 * C1]);
        }
        return;
    }
    if (b == 2) {  // W2b fragments: 768 frags
        for (int f = tid; f < 768; f += 256) {
            const int lane = f & 63, kc = (f >> 6) & 3, nt = f >> 8;
            const int q = lane >> 4, c = lane & 15;
            const int col = nt * 16 + c;
            const int k0 = kc * 32 + q * 8;
            bf16x8 v = 0;
            if (col < CLASSES) {
                const float* wp = W2 + (size_t)k0 * CLASSES + col;
                v = pack8(wp[0], wp[CLASSES], wp[2 * CLASSES], wp[3 * CLASSES],
                          wp[4 * CLASSES], wp[5 * CLASSES], wp[6 * CLASSES], wp[7 * CLASSES]);
            }
            *(bf16x8*)(W2b + (size_t)f * 8) = v;
        }
        return;
    }
    {   // va1: thread (k, half) computes 4 heads x {src,dst}
        const int k = tid >> 1, half = tid & 1;
        const float* wrow = W1 + (size_t)k * C1 + half * 64;
        #pragma unroll
        for (int hh = 0; hh < 4; ++hh) {
            const int h = half * 4 + hh;
            float s = 0.f, d = 0.f;
            #pragma unroll
            for (int t = 0; t < 16; ++t) {
                float wv = wrow[hh * 16 + t];
                s += wv * as1[h * HID + t];
                d += wv * ad1[h * HID + t];
            }
            s *= LOG2E; d *= LOG2E;
            va1h[h * 128 + k]       = bf1(s);
            va1l[h * 128 + k]       = bf1(s - bf1f(s));
            va1h[(h + 8) * 128 + k] = bf1(d);
            va1l[(h + 8) * 128 + k] = bf1(d - bf1f(d));
        }
    }
    if (tid < C1) {  // va2: thread k dots W2 row k with a2 vectors
        const float* wrow = W2 + (size_t)tid * CLASSES;
        float s = 0.f, d = 0.f;
        #pragma unroll
        for (int c2 = 0; c2 < CLASSES; ++c2) {
            float wv = wrow[c2];
            s += wv * as2[c2];
            d += wv * ad2[c2];
        }
        s *= LOG2E; d *= LOG2E;
        va2b[0 * 128 + tid] = bf1(s);
        va2b[1 * 128 + tid] = bf1(s - bf1f(s));
        va2b[2 * 128 + tid] = bf1(d);
        va2b[3 * 128 + tid] = bf1(d - bf1f(d));
    }
}

// ---------------- CSR scan ----------------
// scan1: deg totals from u8 partials; ALSO writes pfx8[b][d] = running prefix of
// dst-d counts over partitions < b. Then exclusive scan over (deg_real + 1).
__global__ void scan1_kernel(const unsigned char* __restrict__ partial8,
                             unsigned char* __restrict__ pfx8,
                             int* __restrict__ deg,
                             int* __restrict__ rowptr, int* __restrict__ bsum) {
    __shared__ int sh[256];
    const int tid = threadIdx.x;
    const int base = blockIdx.x * 1024 + tid * 4;  // < PADN always
    int t0 = 0, t1 = 0, t2 = 0, t3 = 0;
    #pragma unroll 8
    for (int b = 0; b < NHIST; ++b) {
        uchar4 pf;
        pf.x = (unsigned char)t0; pf.y = (unsigned char)t1;
        pf.z = (unsigned char)t2; pf.w = (unsigned char)t3;
        *(uchar4*)(pfx8 + (size_t)b * PADN + base) = pf;   // prefix BEFORE block b
        uchar4 p = *(const uchar4*)(partial8 + (size_t)b * PADN + base);
        t0 += p.x; t1 += p.y; t2 += p.z; t3 += p.w;
    }
    int v[4], s[4];
    v[0] = (base + 0 < NN) ? t0 + 1 : 0;
    v[1] = (base + 1 < NN) ? t1 + 1 : 0;
    v[2] = (base + 2 < NN) ? t2 + 1 : 0;
    v[3] = (base + 3 < NN) ? t3 + 1 : 0;
    #pragma unroll
    for (int j = 0; j < 4; ++j)
        if (base + j < NN) deg[base + j] = v[j];  // total incl self-loop
    s[0] = v[0]; s[1] = s[0] + v[1]; s[2] = s[1] + v[2]; s[3] = s[2] + v[3];
    int T = s[3];
    sh[tid] = T;
    __syncthreads();
    for (int off = 1; off < 256; off <<= 1) {
        int xv = (tid >= off) ? sh[tid - off] : 0;
        __syncthreads();
        sh[tid] += xv;
        __syncthreads();
    }
    int excl = sh[tid] - T;
    #pragma unroll
    for (int j = 0; j < 4; ++j)
        if (base + j < NN) rowptr[base + j] = excl + s[j] - v[j];
    if (tid == 255) bsum[blockIdx.x] = sh[255];
}

// finalize rowptr (scan2 fused); self-loop at slot rowptr[i]
__global__ void scan3_kernel(int* __restrict__ rowptr, const int* __restrict__ bsum,
                             unsigned short* __restrict__ csr) {
    __shared__ int ex[64];
    const int tid = threadIdx.x;
    if (tid < 64) {
        int v = (tid < NCHUNKS) ? bsum[tid] : 0;
        int s = v;
        #pragma unroll
        for (int off = 1; off < 64; off <<= 1) {
            int xv = __shfl_up(s, off);
            if (tid >= off) s += xv;
        }
        ex[tid] = s - v;  // exclusive prefix
    }
    __syncthreads();
    int i = blockIdx.x * blockDim.x + tid;
    if (i >= NN) return;
    int rp = rowptr[i] + ex[i >> 10];
    rowptr[i] = rp;
    csr[rp] = (unsigned short)i;  // self-loop first
}

// ---------------- GEMM1 (wave-per-mtile) + MFMA elogit1, FUSED with LDS-free fill ----
// bids 0..NHIST-1: fill partition — slot = rowptr[d] + 1 + pfx8[b][d] + rank8[e].
// NO LDS, NO atomics anywhere in this kernel -> full gemm occupancy.
__global__ __launch_bounds__(256, 4)
void gemm1_fill_kernel(const float* __restrict__ x,
                       const unsigned short* __restrict__ W1b,
                       const unsigned short* __restrict__ va1h,
                       const unsigned short* __restrict__ va1l,
                       const int* __restrict__ ei,
                       const int* __restrict__ rowptr,
                       const unsigned char* __restrict__ pfx8,
                       const unsigned char* __restrict__ rank8,
                       unsigned short* __restrict__ csr,
                       _Float16* __restrict__ h1h,
                       float* __restrict__ e_src, float* __restrict__ e_dst) {
    const int bid = blockIdx.x;
    const int tid = threadIdx.x;
    if (bid < NHIST) {  // -------- fill: pure arithmetic scatter --------
        const int fb = bid;
        const int* sp = ei + fb * EPB;
        const int* dp = ei + EE + fb * EPB;
        const unsigned char* pf = pfx8 + (size_t)fb * PADN;
        const unsigned char* rk = rank8 + (size_t)fb * EPB;
        for (int e0 = tid * 4; e0 < EPB; e0 += 1024) {
            int4 s4 = *(const int4*)(sp + e0);
            int4 d4 = *(const int4*)(dp + e0);
            uchar4 r = *(const uchar4*)(rk + e0);
            csr[rowptr[d4.x] + 1 + pf[d4.x] + r.x] = (unsigned short)s4.x;
            csr[rowptr[d4.y] + 1 + pf[d4.y] + r.y] = (unsigned short)s4.y;
            csr[rowptr[d4.z] + 1 + pf[d4.z] + r.z] = (unsigned short)s4.z;
            csr[rowptr[d4.w] + 1 + pf[d4.w] + r.w] = (unsigned short)s4.w;
        }
        return;
    }
    const int gemmb = bid - NHIST;
    const int w = tid >> 6, lane = tid & 63;
    const int q = lane >> 4, c = lane & 15;
    const int m0 = (gemmb * 4 + w) * 16;

    int row = m0 + c;
    if (row > NN - 1) row = NN - 1;
    bf16x8 afrag[4];
    #pragma unroll
    for (int kc = 0; kc < 4; ++kc) {
        const float* xp = x + (size_t)row * F_IN + kc * 32 + q * 8;
        float4 p0 = *(const float4*)xp;
        float4 p1 = *(const float4*)(xp + 4);
        afrag[kc] = pack8(p0.x, p0.y, p0.z, p0.w, p1.x, p1.y, p1.z, p1.w);
    }

    // e-operand fragments from prep (L2-hot 8KB) and e-MFMA
    {
        f32x4 acce = {0.f, 0.f, 0.f, 0.f};
        #pragma unroll
        for (int kc = 0; kc < 4; ++kc) {
            const int coloff = kc * 32 + q * 8;
            bf16x8 beh = *(const bf16x8*)(va1h + c * 128 + coloff);
            bf16x8 bel = *(const bf16x8*)(va1l + c * 128 + coloff);
            acce = __builtin_amdgcn_mfma_f32_16x16x32_bf16(afrag[kc], beh, acce, 0, 0, 0);
            acce = __builtin_amdgcn_mfma_f32_16x16x32_bf16(afrag[kc], bel, acce, 0, 0, 0);
        }
        float* ep = (c < 8) ? e_src : e_dst;
        const int cc = c & 7;
        #pragma unroll
        for (int r = 0; r < 4; ++r) {
            const int ro = m0 + q * 4 + r;
            if (ro < NN) ep[(size_t)ro * HEADS + cc] = acce[r];
        }
    }

    // main GEMM: 8 n-tiles, B frags from preconverted L2-hot W1b
    #pragma unroll 2
    for (int nt = 0; nt < 8; ++nt) {
        bf16x8 bf0 = *(const bf16x8*)(W1b + (size_t)((nt * 4 + 0) * 64 + lane) * 8);
        bf16x8 bf1_ = *(const bf16x8*)(W1b + (size_t)((nt * 4 + 1) * 64 + lane) * 8);
        bf16x8 bf2 = *(const bf16x8*)(W1b + (size_t)((nt * 4 + 2) * 64 + lane) * 8);
        bf16x8 bf3 = *(const bf16x8*)(W1b + (size_t)((nt * 4 + 3) * 64 + lane) * 8);
        f32x4 a = {0.f, 0.f, 0.f, 0.f};
        a = __builtin_amdgcn_mfma_f32_16x16x32_bf16(afrag[0], bf0, a, 0, 0, 0);
        a = __builtin_amdgcn_mfma_f32_16x16x32_bf16(afrag[1], bf1_, a, 0, 0, 0);
        a = __builtin_amdgcn_mfma_f32_16x16x32_bf16(afrag[2], bf2, a, 0, 0, 0);
        a = __builtin_amdgcn_mfma_f32_16x16x32_bf16(afrag[3], bf3, a, 0, 0, 0);
        #pragma unroll
        for (int r = 0; r < 4; ++r) {
            const int ro = m0 + q * 4 + r;
            if (ro < NN) h1h[(size_t)ro * C1 + nt * 16 + c] = (_Float16)a[r];
        }
    }
}

// ---------------- layer-1 aggregation: dst-per-group, 8-edge pipeline ----------------
// block = 64 = 1 wave = 4 groups of 16 lanes; each group owns one dst node.
__global__ __launch_bounds__(64)
void agg1_kernel(const _Float16* __restrict__ h1h,
                 const float* __restrict__ e_src, const float* __restrict__ e_dst,
                 const int* __restrict__ rowptr, const int* __restrict__ deg,
                 const unsigned short* __restrict__ csr,
                 const float* __restrict__ b1, unsigned short* __restrict__ hmid) {
    const int tid = threadIdx.x;
    const int l = tid & 15;                      // channel-lane: channels 8l..8l+7
    const int d = blockIdx.x * 4 + (tid >> 4);   // group = dst (grid*4 == NN exactly)
    const int hd = l >> 1;
    const float ed = e_dst[(size_t)d * HEADS + hd];  // pre-scaled by log2e
    const int start = rowptr[d];
    const int cnt = deg[d];

    float denom = 0.f;
    float acc[8] = {0.f, 0.f, 0.f, 0.f, 0.f, 0.f, 0.f, 0.f};

    for (int i = 0; i < cnt; i += 8) {
        int s[8];
        #pragma unroll
        for (int e = 0; e < 8; ++e)
            s[e] = csr[start + ((i + e < cnt) ? i + e : i)];
        float es[8];
        #pragma unroll
        for (int e = 0; e < 8; ++e)
            es[e] = e_src[(size_t)s[e] * HEADS + hd];
        h16x8 g[8];
        #pragma unroll
        for (int e = 0; e < 8; ++e)
            g[e] = *(const h16x8*)(h1h + (size_t)s[e] * C1 + 8 * l);
        float w[8];
        #pragma unroll
        for (int e = 0; e < 8; ++e) {
            float we = fexp2(lrelu(es[e] + ed));
            w[e] = (i + e < cnt) ? we : 0.f;
            denom += w[e];
        }
        #pragma unroll
        for (int e = 0; e < 8; ++e) {
            #pragma unroll
            for (int j = 0; j < 8; ++j)   // v_fma_mix_f32: (float)f16 * f32 + f32
                acc[j] = fmaf((float)g[e][j], w[e], acc[j]);
        }
    }
    const float inv = 1.f / (denom + 1e-16f);
    float o[8];
    #pragma unroll
    for (int k = 0; k < 8; ++k) {
        float t = acc[k] * inv + b1[8 * l + k];
        o[k] = (t > 0.f) ? t : fexp2(t * LOG2E) - 1.f;  // elu (bf16-rounded after)
    }
    uint4 st;
    st.x = cvtpk(o[0], o[1]);
    st.y = cvtpk(o[2], o[3]);
    st.z = cvtpk(o[4], o[5]);
    st.w = cvtpk(o[6], o[7]);
    *(uint4*)(hmid + (size_t)d * C1 + 8 * l) = st;  // bf16 row, 16B/lane
}

// ---------------- GEMM2 (bf16 A direct, preconverted W2b) + MFMA elogit2 ----------------
__global__ __launch_bounds__(256, 4)
void gemm2_kernel(const unsigned short* __restrict__ hmid,
                  const unsigned short* __restrict__ W2b,
                  const unsigned short* __restrict__ va2b,
                  _Float16* __restrict__ h2h,
                  float* __restrict__ e_src, float* __restrict__ e_dst) {
    const int tid = threadIdx.x;
    const int w = tid >> 6, lane = tid & 63;
    const int q = lane >> 4, c = lane & 15;

    const int m0 = (blockIdx.x * 4 + w) * 16;
    if (m0 >= NN) return;
    int row = m0 + c;
    if (row > NN - 1) row = NN - 1;
    bf16x8 afrag[4];
    #pragma unroll
    for (int kc = 0; kc < 4; ++kc)
        afrag[kc] = *(const bf16x8*)(hmid + (size_t)row * C1 + kc * 32 + q * 8);  // no converts

    bf16x8 bfrag[3][4];
    #pragma unroll
    for (int nt = 0; nt < 3; ++nt)
        #pragma unroll
        for (int kc = 0; kc < 4; ++kc)
            bfrag[nt][kc] = *(const bf16x8*)(W2b + (size_t)((nt * 4 + kc) * 64 + lane) * 8);
    // e-tile cols: 0=src_hi, 1=src_lo, 2=dst_hi, 3=dst_lo (from prep, 1KB L2-hot)
    bf16x8 bfe[4];
    #pragma unroll
    for (int kc = 0; kc < 4; ++kc) {
        bf16x8 bb = 0;
        if (c < 4) bb = *(const bf16x8*)(va2b + c * 128 + kc * 32 + q * 8);
        bfe[kc] = bb;
    }

    f32x4 acc[3] = {{0.f,0.f,0.f,0.f},{0.f,0.f,0.f,0.f},{0.f,0.f,0.f,0.f}};
    f32x4 acce = {0.f, 0.f, 0.f, 0.f};
    #pragma unroll
    for (int kc = 0; kc < 4; ++kc) {
        acc[0] = __builtin_amdgcn_mfma_f32_16x16x32_bf16(afrag[kc], bfrag[0][kc], acc[0], 0, 0, 0);
        acc[1] = __builtin_amdgcn_mfma_f32_16x16x32_bf16(afrag[kc], bfrag[1][kc], acc[1], 0, 0, 0);
        acc[2] = __builtin_amdgcn_mfma_f32_16x16x32_bf16(afrag[kc], bfrag[2][kc], acc[2], 0, 0, 0);
        acce   = __builtin_amdgcn_mfma_f32_16x16x32_bf16(afrag[kc], bfe[kc],      acce,   0, 0, 0);
    }
    #pragma unroll
    for (int r = 0; r < 4; ++r) {
        const int ro = m0 + q * 4 + r;
        // combine hi+lo columns: cols (0,1) -> e_src, cols (2,3) -> e_dst
        float v = acce[r] + __shfl_xor(acce[r], 1);
        if (ro < NN) {
            #pragma unroll
            for (int nt = 0; nt < 3; ++nt) {
                const int col = nt * 16 + c;
                if (col < CLASSES)
                    h2h[(size_t)ro * CLASSES + col] = (_Float16)acc[nt][r];
            }
            if (c == 0) e_src[ro] = v;
            if (c == 2) e_dst[ro] = v;
        }
    }
}

// ---------------- layer-2 aggregation: dst-per-group, 8-edge pipeline ----------------
// block = 64 = 1 wave = 3 groups of 20 lanes (lanes 60..63 idle); 3 dst/block.
__global__ __launch_bounds__(64)
void agg2_kernel(const _Float16* __restrict__ h2h,
                 const float* __restrict__ e_src, const float* __restrict__ e_dst,
                 const int* __restrict__ rowptr, const int* __restrict__ deg,
                 const unsigned short* __restrict__ csr,
                 const float* __restrict__ b2, float* __restrict__ out) {
    const int tid = threadIdx.x;
    const int eg = tid / 20;      // 0..2 active groups, 3 = idle lanes 60..63
    const int c  = tid % 20;
    const int d = blockIdx.x * 3 + eg;
    const bool live = (eg < 3) && (d < NN);
    const int dcl = live ? d : 0;
    const float ed = e_dst[dcl];   // pre-scaled by log2e
    const int start = rowptr[dcl];
    const int cnt = live ? deg[dcl] : 0;

    float denom = 0.f, acc0 = 0.f, acc1 = 0.f;
    for (int i = 0; i < cnt; i += 8) {
        int s[8];
        #pragma unroll
        for (int e = 0; e < 8; ++e)
            s[e] = csr[start + ((i + e < cnt) ? i + e : i)];
        float es[8];
        #pragma unroll
        for (int e = 0; e < 8; ++e)
            es[e] = e_src[s[e]];
        h16x2 g[8];
        #pragma unroll
        for (int e = 0; e < 8; ++e)
            g[e] = *(const h16x2*)(h2h + (size_t)s[e] * CLASSES + 2 * c);
        float w[8];
        #pragma unroll
        for (int e = 0; e < 8; ++e) {
            float we = fexp2(lrelu(es[e] + ed));
            w[e] = (i + e < cnt) ? we : 0.f;
            denom += w[e];
        }
        #pragma unroll
        for (int e = 0; e < 8; ++e) {
            acc0 = fmaf((float)g[e][0], w[e], acc0);
            acc1 = fmaf((float)g[e][1], w[e], acc1);
        }
    }
    if (live) {
        const float inv = 1.f / (denom + 1e-16f);
        float2 o;
        o.x = acc0 * inv + b2[2 * c];
        o.y = acc1 * inv + b2[2 * c + 1];
        *(float2*)(out + (size_t)d * CLASSES + 2 * c) = o;
    }
}

extern "C" void kernel_launch(void* const* d_in, const int* in_sizes, int n_in,
                              void* d_out, int out_size, void* d_ws, size_t ws_size,
                              hipStream_t stream) {
    const float* x      = (const float*)d_in[0];
    const int*   ei     = (const int*)d_in[1];
    const float* W1     = (const float*)d_in[2];
    const float* a_src1 = (const float*)d_in[3];
    const float* a_dst1 = (const float*)d_in[4];
    const float* b1     = (const float*)d_in[5];
    const float* W2     = (const float*)d_in[6];
    const float* a_src2 = (const float*)d_in[7];
    const float* a_dst2 = (const float*)d_in[8];
    const float* b2     = (const float*)d_in[9];
    float* out = (float*)d_out;

    char* ws = (char*)d_ws;
    size_t off = 0;
    auto alloc = [&](size_t bytes) { char* p = ws + off; off += (bytes + 255) & ~(size_t)255; return p; };
    _Float16* h1h = (_Float16*)alloc((size_t)NN * C1 * 2);
    _Float16* h2h = (_Float16*)alloc((size_t)NN * CLASSES * 2);
    unsigned short* hmidb = (unsigned short*)alloc((size_t)NN * C1 * 2);
    float* e_src1 = (float*)alloc((size_t)NN * HEADS * 4);
    float* e_dst1 = (float*)alloc((size_t)NN * HEADS * 4);
    float* e_src2 = (float*)alloc((size_t)NN * 4);
    float* e_dst2 = (float*)alloc((size_t)NN * 4);
    int*   deg    = (int*)alloc((size_t)NN * 4);
    int*   rowptr = (int*)alloc((size_t)NN * 4);
    unsigned short* csr  = (unsigned short*)alloc((size_t)ET * 2);
    int*   bsum   = (int*)alloc(256 * 4);
    unsigned short* va1h = (unsigned short*)alloc(16 * 128 * 2);
    unsigned short* va1l = (unsigned short*)alloc(16 * 128 * 2);
    unsigned short* va2b = (unsigned short*)alloc(4 * 128 * 2);
    unsigned short* W1b  = (unsigned short*)alloc(2048 * 8 * 2);
    unsigned short* W2b  = (unsigned short*)alloc(768 * 8 * 2);
    unsigned char* partial8 = (unsigned char*)alloc((size_t)NHIST * PADN);
    unsigned char* pfx8     = (unsigned char*)alloc((size_t)NHIST * PADN);
    unsigned char* rank8    = (unsigned char*)alloc((size_t)EE);

    prep_kernel<<<3 + NHIST, 256, 0, stream>>>(W1, a_src1, a_dst1, W2, a_src2, a_dst2, ei,
                                               va1h, va1l, va2b, W1b, W2b, partial8, rank8);
    scan1_kernel<<<NCHUNKS, 256, 0, stream>>>(partial8, pfx8, deg, rowptr, bsum);
    scan3_kernel<<<(NN + 255) / 256, 256, 0, stream>>>(rowptr, bsum, csr);
    gemm1_fill_kernel<<<NHIST + GB, 256, 0, stream>>>(x, W1b, va1h, va1l, ei, rowptr, pfx8,
                                                      rank8, csr, h1h, e_src1, e_dst1);

    agg1_kernel<<<NN / 4, 64, 0, stream>>>(h1h, e_src1, e_dst1, rowptr, deg, csr, b1, hmidb);

    gemm2_kernel<<<(NN + 63) / 64, 256, 0, stream>>>(hmidb, W2b, va2b, h2h, e_src2, e_dst2);
    agg2_kernel<<<(NN + 2) / 3, 64, 0, stream>>>(h2h, e_src2, e_dst2, rowptr, deg, csr, b2, out);
}

// Round 11
// 196.015 us; speedup vs baseline: 1.0531x; 1.0531x over previous
//
#include <hip/hip_runtime.h>
#include <math.h>

#define NN 50000
#define EE 800000
#define ET (EE + NN)      // edges + self loops
#define F_IN 128
#define HEADS 8
#define HID 16
#define C1 (HEADS * HID)  // 128
#define CLASSES 40
#define NEG_SLOPE 0.2f
#define LOG2E 1.4426950408889634f

#define NCHUNKS ((NN + 1023) / 1024)  // 49
#define NHIST 64                      // edge partitions (hist)
#define EPB (EE / NHIST)              // 12500 edges per partition
#define PADN (NCHUNKS * 1024)         // 50176 padded dst slots
#define LDSW (PADN / 4)               // 12544 u32 words of packed-u8 counters
#define GB ((NN + 63) / 64)           // 782 gemm1 blocks (64 rows each)
#define FSUB 5                        // fill sub-chunks per partition
#define FPB (EPB / FSUB)              // 2500 edges per fill block
#define FILLB (NHIST * FSUB)          // 320 fill blocks

typedef __attribute__((ext_vector_type(8))) short bf16x8;
typedef __attribute__((ext_vector_type(4))) float f32x4;
typedef __attribute__((ext_vector_type(8))) _Float16 h16x8;
typedef __attribute__((ext_vector_type(2))) _Float16 h16x2;

__device__ __forceinline__ unsigned cvtpk(float a, float b) {
    unsigned r;
    asm("v_cvt_pk_bf16_f32 %0, %1, %2" : "=v"(r) : "v"(a), "v"(b));
    return r;
}
__device__ __forceinline__ float fexp2(float x) {
    float r;
    asm("v_exp_f32 %0, %1\n\ts_nop 0" : "=v"(r) : "v"(x));
    return r;
}
__device__ __forceinline__ float bflo(unsigned u) { return __uint_as_float(u << 16); }
__device__ __forceinline__ float bfhi(unsigned u) { return __uint_as_float(u & 0xffff0000u); }
__device__ __forceinline__ float lrelu(float a) { return fmaxf(a, NEG_SLOPE * a); }
__device__ __forceinline__ unsigned short bf1(float a) { return (unsigned short)cvtpk(a, a); }
__device__ __forceinline__ float bf1f(float a) { return bflo(cvtpk(a, a)); }
__device__ __forceinline__ bf16x8 pack8(float f0, float f1, float f2, float f3,
                                        float f4, float f5, float f6, float f7) {
    union { unsigned u[4]; bf16x8 v; } U;
    U.u[0] = cvtpk(f0, f1);
    U.u[1] = cvtpk(f2, f3);
    U.u[2] = cvtpk(f4, f5);
    U.u[3] = cvtpk(f6, f7);
    return U.v;
}

// ---------------- prep ----------------
// block 0: va1 (16x128 hi/lo bf16, frag layout) + va2 (4x128 bf16)
// block 1: W1b — W1 as bf16 MFMA fragments
// block 2: W2b — W2 fragments, cols >= CLASSES zeroed
// blocks 3..3+NHIST: LDS-histogram degree count, u8-packed; the atomicAdd return
//                    value IS each edge's within-partition rank -> rank8[] (coalesced).
__global__ void prep_kernel(const float* __restrict__ W1,
                            const float* __restrict__ as1, const float* __restrict__ ad1,
                            const float* __restrict__ W2,
                            const float* __restrict__ as2, const float* __restrict__ ad2,
                            const int* __restrict__ ei,
                            unsigned short* __restrict__ va1h, unsigned short* __restrict__ va1l,
                            unsigned short* __restrict__ va2b,
                            unsigned short* __restrict__ W1b, unsigned short* __restrict__ W2b,
                            unsigned char* __restrict__ partial8,
                            unsigned char* __restrict__ rank8) {
    const int tid = threadIdx.x;
    const int b = blockIdx.x;
    if (b >= 3) {  // -------- histogram count + rank capture, u8-packed LDS --------
        __shared__ unsigned lhist[LDSW];
        for (int i = tid; i < LDSW; i += 256) lhist[i] = 0;
        __syncthreads();
        const int hb = b - 3;
        const int* dp = ei + EE + hb * EPB;
        unsigned char* rk = rank8 + (size_t)hb * EPB;
        for (int e0 = tid * 4; e0 < EPB; e0 += 1024) {
            int4 d4 = *(const int4*)(dp + e0);
            uchar4 r;
            {
                const unsigned d = (unsigned)d4.x, sh8 = (d & 3) << 3;
                unsigned old = atomicAdd(&lhist[d >> 2], 1u << sh8);
                r.x = (unsigned char)((old >> sh8) & 0xff);
            }
            {
                const unsigned d = (unsigned)d4.y, sh8 = (d & 3) << 3;
                unsigned old = atomicAdd(&lhist[d >> 2], 1u << sh8);
                r.y = (unsigned char)((old >> sh8) & 0xff);
            }
            {
                const unsigned d = (unsigned)d4.z, sh8 = (d & 3) << 3;
                unsigned old = atomicAdd(&lhist[d >> 2], 1u << sh8);
                r.z = (unsigned char)((old >> sh8) & 0xff);
            }
            {
                const unsigned d = (unsigned)d4.w, sh8 = (d & 3) << 3;
                unsigned old = atomicAdd(&lhist[d >> 2], 1u << sh8);
                r.w = (unsigned char)((old >> sh8) & 0xff);
            }
            *(uchar4*)(rk + e0) = r;  // coalesced rank store
        }
        __syncthreads();
        unsigned* pb = (unsigned*)(partial8 + (size_t)hb * PADN);
        for (int i = tid; i < LDSW; i += 256) pb[i] = lhist[i];
        return;
    }
    if (b == 1) {  // W1b fragments: 2048 frags, 8 per thread
        for (int f = tid; f < 2048; f += 256) {
            const int lane = f & 63, kc = (f >> 6) & 3, ntw = f >> 8;
            const int q = lane >> 4, c = lane & 15;
            const int col = ntw * 16 + c;
            const int k0 = kc * 32 + q * 8;
            const float* wp = W1 + (size_t)k0 * C1 + col;
            *(bf16x8*)(W1b + (size_t)f * 8) =
                pack8(wp[0], wp[C1], wp[2 * C1], wp[3 * C1],
                      wp[4 * C1], wp[5 * C1], wp[6 * C1], wp[7 * C1]);
        }
        return;
    }
    if (b == 2) {  // W2b fragments: 768 frags
        for (int f = tid; f < 768; f += 256) {
            const int lane = f & 63, kc = (f >> 6) & 3, nt = f >> 8;
            const int q = lane >> 4, c = lane & 15;
            const int col = nt * 16 + c;
            const int k0 = kc * 32 + q * 8;
            bf16x8 v = 0;
            if (col < CLASSES) {
                const float* wp = W2 + (size_t)k0 * CLASSES + col;
                v = pack8(wp[0], wp[CLASSES], wp[2 * CLASSES], wp[3 * CLASSES],
                          wp[4 * CLASSES], wp[5 * CLASSES], wp[6 * CLASSES], wp[7 * CLASSES]);
            }
            *(bf16x8*)(W2b + (size_t)f * 8) = v;
        }
        return;
    }
    {   // va1: thread (k, half) computes 4 heads x {src,dst}
        const int k = tid >> 1, half = tid & 1;
        const float* wrow = W1 + (size_t)k * C1 + half * 64;
        #pragma unroll
        for (int hh = 0; hh < 4; ++hh) {
            const int h = half * 4 + hh;
            float s = 0.f, d = 0.f;
            #pragma unroll
            for (int t = 0; t < 16; ++t) {
                float wv = wrow[hh * 16 + t];
                s += wv * as1[h * HID + t];
                d += wv * ad1[h * HID + t];
            }
            s *= LOG2E; d *= LOG2E;
            va1h[h * 128 + k]       = bf1(s);
            va1l[h * 128 + k]       = bf1(s - bf1f(s));
            va1h[(h + 8) * 128 + k] = bf1(d);
            va1l[(h + 8) * 128 + k] = bf1(d - bf1f(d));
        }
    }
    if (tid < C1) {  // va2: thread k dots W2 row k with a2 vectors
        const float* wrow = W2 + (size_t)tid * CLASSES;
        float s = 0.f, d = 0.f;
        #pragma unroll
        for (int c2 = 0; c2 < CLASSES; ++c2) {
            float wv = wrow[c2];
            s += wv * as2[c2];
            d += wv * ad2[c2];
        }
        s *= LOG2E; d *= LOG2E;
        va2b[0 * 128 + tid] = bf1(s);
        va2b[1 * 128 + tid] = bf1(s - bf1f(s));
        va2b[2 * 128 + tid] = bf1(d);
        va2b[3 * 128 + tid] = bf1(d - bf1f(d));
    }
}

// ---------------- CSR scan ----------------
// scan1: deg totals from u8 partials; ALSO writes pfx8[b][d] = running prefix of
// dst-d counts over partitions < b. Then exclusive scan over (deg_real + 1).
__global__ void scan1_kernel(const unsigned char* __restrict__ partial8,
                             unsigned char* __restrict__ pfx8,
                             int* __restrict__ deg,
                             int* __restrict__ rowptr, int* __restrict__ bsum) {
    __shared__ int sh[256];
    const int tid = threadIdx.x;
    const int base = blockIdx.x * 1024 + tid * 4;  // < PADN always
    int t0 = 0, t1 = 0, t2 = 0, t3 = 0;
    #pragma unroll 8
    for (int b = 0; b < NHIST; ++b) {
        uchar4 pf;
        pf.x = (unsigned char)t0; pf.y = (unsigned char)t1;
        pf.z = (unsigned char)t2; pf.w = (unsigned char)t3;
        *(uchar4*)(pfx8 + (size_t)b * PADN + base) = pf;   // prefix BEFORE block b
        uchar4 p = *(const uchar4*)(partial8 + (size_t)b * PADN + base);
        t0 += p.x; t1 += p.y; t2 += p.z; t3 += p.w;
    }
    int v[4], s[4];
    v[0] = (base + 0 < NN) ? t0 + 1 : 0;
    v[1] = (base + 1 < NN) ? t1 + 1 : 0;
    v[2] = (base + 2 < NN) ? t2 + 1 : 0;
    v[3] = (base + 3 < NN) ? t3 + 1 : 0;
    #pragma unroll
    for (int j = 0; j < 4; ++j)
        if (base + j < NN) deg[base + j] = v[j];  // total incl self-loop
    s[0] = v[0]; s[1] = s[0] + v[1]; s[2] = s[1] + v[2]; s[3] = s[2] + v[3];
    int T = s[3];
    sh[tid] = T;
    __syncthreads();
    for (int off = 1; off < 256; off <<= 1) {
        int xv = (tid >= off) ? sh[tid - off] : 0;
        __syncthreads();
        sh[tid] += xv;
        __syncthreads();
    }
    int excl = sh[tid] - T;
    #pragma unroll
    for (int j = 0; j < 4; ++j)
        if (base + j < NN) rowptr[base + j] = excl + s[j] - v[j];
    if (tid == 255) bsum[blockIdx.x] = sh[255];
}

// finalize rowptr (scan2 fused); self-loop at slot rowptr[i]
__global__ void scan3_kernel(int* __restrict__ rowptr, const int* __restrict__ bsum,
                             unsigned short* __restrict__ csr) {
    __shared__ int ex[64];
    const int tid = threadIdx.x;
    if (tid < 64) {
        int v = (tid < NCHUNKS) ? bsum[tid] : 0;
        int s = v;
        #pragma unroll
        for (int off = 1; off < 64; off <<= 1) {
            int xv = __shfl_up(s, off);
            if (tid >= off) s += xv;
        }
        ex[tid] = s - v;  // exclusive prefix
    }
    __syncthreads();
    int i = blockIdx.x * blockDim.x + tid;
    if (i >= NN) return;
    int rp = rowptr[i] + ex[i >> 10];
    rowptr[i] = rp;
    csr[rp] = (unsigned short)i;  // self-loop first
}

// ---------------- GEMM1 (wave-per-mtile) + MFMA elogit1, FUSED with LDS-free fill ----
// bids 0..FILLB-1: fill chunk (2500 edges) — slot = rowptr[d]+1+pfx8[part][d]+rank8[e].
// NO LDS, NO atomics anywhere -> full occupancy. Fill blocks first (head start).
__global__ __launch_bounds__(256, 4)
void gemm1_fill_kernel(const float* __restrict__ x,
                       const unsigned short* __restrict__ W1b,
                       const unsigned short* __restrict__ va1h,
                       const unsigned short* __restrict__ va1l,
                       const int* __restrict__ ei,
                       const int* __restrict__ rowptr,
                       const unsigned char* __restrict__ pfx8,
                       const unsigned char* __restrict__ rank8,
                       unsigned short* __restrict__ csr,
                       _Float16* __restrict__ h1h,
                       float* __restrict__ e_src, float* __restrict__ e_dst) {
    const int bid = blockIdx.x;
    const int tid = threadIdx.x;
    if (bid < FILLB) {  // -------- fill: pure arithmetic scatter, 2500 edges --------
        const int part = bid / FSUB;
        const int chunkoff = (bid % FSUB) * FPB;
        const int gbase = part * EPB + chunkoff;
        const int* sp = ei + gbase;
        const int* dp = ei + EE + gbase;
        const unsigned char* pf = pfx8 + (size_t)part * PADN;
        const unsigned char* rk = rank8 + (size_t)part * EPB + chunkoff;
        for (int e0 = tid * 4; e0 < FPB; e0 += 1024) {
            int4 s4 = *(const int4*)(sp + e0);
            int4 d4 = *(const int4*)(dp + e0);
            uchar4 r = *(const uchar4*)(rk + e0);
            csr[rowptr[d4.x] + 1 + pf[d4.x] + r.x] = (unsigned short)s4.x;
            csr[rowptr[d4.y] + 1 + pf[d4.y] + r.y] = (unsigned short)s4.y;
            csr[rowptr[d4.z] + 1 + pf[d4.z] + r.z] = (unsigned short)s4.z;
            csr[rowptr[d4.w] + 1 + pf[d4.w] + r.w] = (unsigned short)s4.w;
        }
        return;
    }
    const int gemmb = bid - FILLB;
    const int w = tid >> 6, lane = tid & 63;
    const int q = lane >> 4, c = lane & 15;
    const int m0 = (gemmb * 4 + w) * 16;

    int row = m0 + c;
    if (row > NN - 1) row = NN - 1;
    bf16x8 afrag[4];
    #pragma unroll
    for (int kc = 0; kc < 4; ++kc) {
        const float* xp = x + (size_t)row * F_IN + kc * 32 + q * 8;
        float4 p0 = *(const float4*)xp;
        float4 p1 = *(const float4*)(xp + 4);
        afrag[kc] = pack8(p0.x, p0.y, p0.z, p0.w, p1.x, p1.y, p1.z, p1.w);
    }

    // e-operand fragments from prep (L2-hot 8KB) and e-MFMA
    {
        f32x4 acce = {0.f, 0.f, 0.f, 0.f};
        #pragma unroll
        for (int kc = 0; kc < 4; ++kc) {
            const int coloff = kc * 32 + q * 8;
            bf16x8 beh = *(const bf16x8*)(va1h + c * 128 + coloff);
            bf16x8 bel = *(const bf16x8*)(va1l + c * 128 + coloff);
            acce = __builtin_amdgcn_mfma_f32_16x16x32_bf16(afrag[kc], beh, acce, 0, 0, 0);
            acce = __builtin_amdgcn_mfma_f32_16x16x32_bf16(afrag[kc], bel, acce, 0, 0, 0);
        }
        float* ep = (c < 8) ? e_src : e_dst;
        const int cc = c & 7;
        #pragma unroll
        for (int r = 0; r < 4; ++r) {
            const int ro = m0 + q * 4 + r;
            if (ro < NN) ep[(size_t)ro * HEADS + cc] = acce[r];
        }
    }

    // main GEMM: 8 n-tiles, B frags from preconverted L2-hot W1b
    #pragma unroll 2
    for (int nt = 0; nt < 8; ++nt) {
        bf16x8 bf0 = *(const bf16x8*)(W1b + (size_t)((nt * 4 + 0) * 64 + lane) * 8);
        bf16x8 bf1_ = *(const bf16x8*)(W1b + (size_t)((nt * 4 + 1) * 64 + lane) * 8);
        bf16x8 bf2 = *(const bf16x8*)(W1b + (size_t)((nt * 4 + 2) * 64 + lane) * 8);
        bf16x8 bf3 = *(const bf16x8*)(W1b + (size_t)((nt * 4 + 3) * 64 + lane) * 8);
        f32x4 a = {0.f, 0.f, 0.f, 0.f};
        a = __builtin_amdgcn_mfma_f32_16x16x32_bf16(afrag[0], bf0, a, 0, 0, 0);
        a = __builtin_amdgcn_mfma_f32_16x16x32_bf16(afrag[1], bf1_, a, 0, 0, 0);
        a = __builtin_amdgcn_mfma_f32_16x16x32_bf16(afrag[2], bf2, a, 0, 0, 0);
        a = __builtin_amdgcn_mfma_f32_16x16x32_bf16(afrag[3], bf3, a, 0, 0, 0);
        #pragma unroll
        for (int r = 0; r < 4; ++r) {
            const int ro = m0 + q * 4 + r;
            if (ro < NN) h1h[(size_t)ro * C1 + nt * 16 + c] = (_Float16)a[r];
        }
    }
}

// ---------------- layer-1 aggregation FUSED with GEMM2 + elogit2 ----------------
// block = 256 = 16 groups of 16 lanes; each group owns one dst -> block = one m-tile.
// Agg phase: 8-edge pipeline per group, result (bf16) staged in LDS tile [16][132].
// GEMM2 phase: wave 0 computes h2 + e2 for the block's 16 rows (hmid never hits HBM).
__global__ __launch_bounds__(256)
void agg1_gemm2_kernel(const _Float16* __restrict__ h1h,
                       const float* __restrict__ e_src, const float* __restrict__ e_dst,
                       const int* __restrict__ rowptr, const int* __restrict__ deg,
                       const unsigned short* __restrict__ csr,
                       const float* __restrict__ b1,
                       const unsigned short* __restrict__ W2b,
                       const unsigned short* __restrict__ va2b,
                       _Float16* __restrict__ h2h,
                       float* __restrict__ e_src2, float* __restrict__ e_dst2) {
    __shared__ unsigned short hm[16][132];  // bf16 m-tile, +4 pad (bank spread)
    const int tid = threadIdx.x;
    const int grp = tid >> 4;                   // 0..15 = row in tile
    const int l = tid & 15;                     // channel-lane: channels 8l..8l+7
    const int d = blockIdx.x * 16 + grp;        // grid*16 == NN exactly
    const int hd = l >> 1;
    const float ed = e_dst[(size_t)d * HEADS + hd];  // pre-scaled by log2e
    const int start = rowptr[d];
    const int cnt = deg[d];

    float denom = 0.f;
    float acc[8] = {0.f, 0.f, 0.f, 0.f, 0.f, 0.f, 0.f, 0.f};

    for (int i = 0; i < cnt; i += 8) {
        int s[8];
        #pragma unroll
        for (int e = 0; e < 8; ++e)
            s[e] = csr[start + ((i + e < cnt) ? i + e : i)];
        float es[8];
        #pragma unroll
        for (int e = 0; e < 8; ++e)
            es[e] = e_src[(size_t)s[e] * HEADS + hd];
        h16x8 g[8];
        #pragma unroll
        for (int e = 0; e < 8; ++e)
            g[e] = *(const h16x8*)(h1h + (size_t)s[e] * C1 + 8 * l);
        float w[8];
        #pragma unroll
        for (int e = 0; e < 8; ++e) {
            float we = fexp2(lrelu(es[e] + ed));
            w[e] = (i + e < cnt) ? we : 0.f;
            denom += w[e];
        }
        #pragma unroll
        for (int e = 0; e < 8; ++e) {
            #pragma unroll
            for (int j = 0; j < 8; ++j)   // v_fma_mix_f32: (float)f16 * f32 + f32
                acc[j] = fmaf((float)g[e][j], w[e], acc[j]);
        }
    }
    const float inv = 1.f / (denom + 1e-16f);
    float o[8];
    #pragma unroll
    for (int k = 0; k < 8; ++k) {
        float t = acc[k] * inv + b1[8 * l + k];
        o[k] = (t > 0.f) ? t : fexp2(t * LOG2E) - 1.f;  // elu (bf16-rounded after)
    }
    uint4 st;
    st.x = cvtpk(o[0], o[1]);
    st.y = cvtpk(o[2], o[3]);
    st.z = cvtpk(o[4], o[5]);
    st.w = cvtpk(o[6], o[7]);
    *(uint4*)(&hm[grp][8 * l]) = st;  // bf16 row into LDS tile
    __syncthreads();

    // -------- GEMM2 + elogit2 on this block's 16 rows (wave 0 only) --------
    if (tid < 64) {
        const int lane = tid, q = lane >> 4, c = lane & 15;
        const int m0 = blockIdx.x * 16;
        bf16x8 afrag[4];
        #pragma unroll
        for (int kc = 0; kc < 4; ++kc)
            afrag[kc] = *(const bf16x8*)(&hm[c][kc * 32 + q * 8]);

        bf16x8 bfrag[3][4];
        #pragma unroll
        for (int nt = 0; nt < 3; ++nt)
            #pragma unroll
            for (int kc = 0; kc < 4; ++kc)
                bfrag[nt][kc] = *(const bf16x8*)(W2b + (size_t)((nt * 4 + kc) * 64 + lane) * 8);
        // e-tile cols: 0=src_hi, 1=src_lo, 2=dst_hi, 3=dst_lo (1KB L2-hot)
        bf16x8 bfe[4];
        #pragma unroll
        for (int kc = 0; kc < 4; ++kc) {
            bf16x8 bb = 0;
            if (c < 4) bb = *(const bf16x8*)(va2b + c * 128 + kc * 32 + q * 8);
            bfe[kc] = bb;
        }

        f32x4 a2[3] = {{0.f,0.f,0.f,0.f},{0.f,0.f,0.f,0.f},{0.f,0.f,0.f,0.f}};
        f32x4 acce = {0.f, 0.f, 0.f, 0.f};
        #pragma unroll
        for (int kc = 0; kc < 4; ++kc) {
            a2[0] = __builtin_amdgcn_mfma_f32_16x16x32_bf16(afrag[kc], bfrag[0][kc], a2[0], 0, 0, 0);
            a2[1] = __builtin_amdgcn_mfma_f32_16x16x32_bf16(afrag[kc], bfrag[1][kc], a2[1], 0, 0, 0);
            a2[2] = __builtin_amdgcn_mfma_f32_16x16x32_bf16(afrag[kc], bfrag[2][kc], a2[2], 0, 0, 0);
            acce  = __builtin_amdgcn_mfma_f32_16x16x32_bf16(afrag[kc], bfe[kc],      acce,  0, 0, 0);
        }
        #pragma unroll
        for (int r = 0; r < 4; ++r) {
            const int ro = m0 + q * 4 + r;
            // combine hi+lo columns: cols (0,1) -> e_src2, cols (2,3) -> e_dst2
            float v = acce[r] + __shfl_xor(acce[r], 1);
            #pragma unroll
            for (int nt = 0; nt < 3; ++nt) {
                const int col = nt * 16 + c;
                if (col < CLASSES)
                    h2h[(size_t)ro * CLASSES + col] = (_Float16)a2[nt][r];
            }
            if (c == 0) e_src2[ro] = v;
            if (c == 2) e_dst2[ro] = v;
        }
    }
}

// ---------------- layer-2 aggregation: dst-per-group, 8-edge pipeline ----------------
// block = 64 = 1 wave = 3 groups of 20 lanes (lanes 60..63 idle); 3 dst/block.
__global__ __launch_bounds__(64)
void agg2_kernel(const _Float16* __restrict__ h2h,
                 const float* __restrict__ e_src, const float* __restrict__ e_dst,
                 const int* __restrict__ rowptr, const int* __restrict__ deg,
                 const unsigned short* __restrict__ csr,
                 const float* __restrict__ b2, float* __restrict__ out) {
    const int tid = threadIdx.x;
    const int eg = tid / 20;      // 0..2 active groups, 3 = idle lanes 60..63
    const int c  = tid % 20;
    const int d = blockIdx.x * 3 + eg;
    const bool live = (eg < 3) && (d < NN);
    const int dcl = live ? d : 0;
    const float ed = e_dst[dcl];   // pre-scaled by log2e
    const int start = rowptr[dcl];
    const int cnt = live ? deg[dcl] : 0;

    float denom = 0.f, acc0 = 0.f, acc1 = 0.f;
    for (int i = 0; i < cnt; i += 8) {
        int s[8];
        #pragma unroll
        for (int e = 0; e < 8; ++e)
            s[e] = csr[start + ((i + e < cnt) ? i + e : i)];
        float es[8];
        #pragma unroll
        for (int e = 0; e < 8; ++e)
            es[e] = e_src[s[e]];
        h16x2 g[8];
        #pragma unroll
        for (int e = 0; e < 8; ++e)
            g[e] = *(const h16x2*)(h2h + (size_t)s[e] * CLASSES + 2 * c);
        float w[8];
        #pragma unroll
        for (int e = 0; e < 8; ++e) {
            float we = fexp2(lrelu(es[e] + ed));
            w[e] = (i + e < cnt) ? we : 0.f;
            denom += w[e];
        }
        #pragma unroll
        for (int e = 0; e < 8; ++e) {
            acc0 = fmaf((float)g[e][0], w[e], acc0);
            acc1 = fmaf((float)g[e][1], w[e], acc1);
        }
    }
    if (live) {
        const float inv = 1.f / (denom + 1e-16f);
        float2 o;
        o.x = acc0 * inv + b2[2 * c];
        o.y = acc1 * inv + b2[2 * c + 1];
        *(float2*)(out + (size_t)d * CLASSES + 2 * c) = o;
    }
}

extern "C" void kernel_launch(void* const* d_in, const int* in_sizes, int n_in,
                              void* d_out, int out_size, void* d_ws, size_t ws_size,
                              hipStream_t stream) {
    const float* x      = (const float*)d_in[0];
    const int*   ei     = (const int*)d_in[1];
    const float* W1     = (const float*)d_in[2];
    const float* a_src1 = (const float*)d_in[3];
    const float* a_dst1 = (const float*)d_in[4];
    const float* b1     = (const float*)d_in[5];
    const float* W2     = (const float*)d_in[6];
    const float* a_src2 = (const float*)d_in[7];
    const float* a_dst2 = (const float*)d_in[8];
    const float* b2     = (const float*)d_in[9];
    float* out = (float*)d_out;

    char* ws = (char*)d_ws;
    size_t off = 0;
    auto alloc = [&](size_t bytes) { char* p = ws + off; off += (bytes + 255) & ~(size_t)255; return p; };
    _Float16* h1h = (_Float16*)alloc((size_t)NN * C1 * 2);
    _Float16* h2h = (_Float16*)alloc((size_t)NN * CLASSES * 2);
    float* e_src1 = (float*)alloc((size_t)NN * HEADS * 4);
    float* e_dst1 = (float*)alloc((size_t)NN * HEADS * 4);
    float* e_src2 = (float*)alloc((size_t)NN * 4);
    float* e_dst2 = (float*)alloc((size_t)NN * 4);
    int*   deg    = (int*)alloc((size_t)NN * 4);
    int*   rowptr = (int*)alloc((size_t)NN * 4);
    unsigned short* csr  = (unsigned short*)alloc((size_t)ET * 2);
    int*   bsum   = (int*)alloc(256 * 4);
    unsigned short* va1h = (unsigned short*)alloc(16 * 128 * 2);
    unsigned short* va1l = (unsigned short*)alloc(16 * 128 * 2);
    unsigned short* va2b = (unsigned short*)alloc(4 * 128 * 2);
    unsigned short* W1b  = (unsigned short*)alloc(2048 * 8 * 2);
    unsigned short* W2b  = (unsigned short*)alloc(768 * 8 * 2);
    unsigned char* partial8 = (unsigned char*)alloc((size_t)NHIST * PADN);
    unsigned char* pfx8     = (unsigned char*)alloc((size_t)NHIST * PADN);
    unsigned char* rank8    = (unsigned char*)alloc((size_t)EE);

    prep_kernel<<<3 + NHIST, 256, 0, stream>>>(W1, a_src1, a_dst1, W2, a_src2, a_dst2, ei,
                                               va1h, va1l, va2b, W1b, W2b, partial8, rank8);
    scan1_kernel<<<NCHUNKS, 256, 0, stream>>>(partial8, pfx8, deg, rowptr, bsum);
    scan3_kernel<<<(NN + 255) / 256, 256, 0, stream>>>(rowptr, bsum, csr);
    gemm1_fill_kernel<<<FILLB + GB, 256, 0, stream>>>(x, W1b, va1h, va1l, ei, rowptr, pfx8,
                                                      rank8, csr, h1h, e_src1, e_dst1);

    agg1_gemm2_kernel<<<NN / 16, 256, 0, stream>>>(h1h, e_src1, e_dst1, rowptr, deg, csr, b1,
                                                   W2b, va2b, h2h, e_src2, e_dst2);

    agg2_kernel<<<(NN + 2) / 3, 64, 0, stream>>>(h2h, e_src2, e_dst2, rowptr, deg, csr, b2, out);
}

// Round 13
// 194.645 us; speedup vs baseline: 1.0605x; 1.0070x over previous
//
#include <hip/hip_runtime.h>
#include <math.h>

#define NN 50000
#define EE 800000
#define ET (EE + NN)      // edges + self loops
#define F_IN 128
#define HEADS 8
#define HID 16
#define C1 (HEADS * HID)  // 128
#define CLASSES 40
#define NEG_SLOPE 0.2f
#define LOG2E 1.4426950408889634f

#define NCHUNKS ((NN + 1023) / 1024)  // 49
#define NHIST 160                     // edge partitions; EPB MUST be divisible by 4
#define EPB (EE / NHIST)              // 5000 edges per partition (5000 % 4 == 0)
#define PADN (NCHUNKS * 1024)         // 50176 padded dst slots
#define LDSW (PADN / 4)               // 12544 u32 words of packed-u8 counters
#define GB ((NN + 63) / 64)           // 782 gemm1 blocks (64 rows each)
#define FSUB 5                        // fill sub-chunks per partition
#define FPB (EPB / FSUB)              // 1000 edges per fill block (1000 % 4 == 0)
#define FILLB (NHIST * FSUB)          // 800 fill blocks
#define S3B ((NN + 255) / 256)        // 196 scan3-role blocks

typedef __attribute__((ext_vector_type(8))) short bf16x8;
typedef __attribute__((ext_vector_type(4))) float f32x4;
typedef __attribute__((ext_vector_type(8))) _Float16 h16x8;
typedef __attribute__((ext_vector_type(2))) _Float16 h16x2;

__device__ __forceinline__ unsigned cvtpk(float a, float b) {
    unsigned r;
    asm("v_cvt_pk_bf16_f32 %0, %1, %2" : "=v"(r) : "v"(a), "v"(b));
    return r;
}
__device__ __forceinline__ float fexp2(float x) {
    float r;
    asm("v_exp_f32 %0, %1\n\ts_nop 0" : "=v"(r) : "v"(x));
    return r;
}
__device__ __forceinline__ float bflo(unsigned u) { return __uint_as_float(u << 16); }
__device__ __forceinline__ float bfhi(unsigned u) { return __uint_as_float(u & 0xffff0000u); }
__device__ __forceinline__ float lrelu(float a) { return fmaxf(a, NEG_SLOPE * a); }
__device__ __forceinline__ unsigned short bf1(float a) { return (unsigned short)cvtpk(a, a); }
__device__ __forceinline__ float bf1f(float a) { return bflo(cvtpk(a, a)); }
__device__ __forceinline__ bf16x8 pack8(float f0, float f1, float f2, float f3,
                                        float f4, float f5, float f6, float f7) {
    union { unsigned u[4]; bf16x8 v; } U;
    U.u[0] = cvtpk(f0, f1);
    U.u[1] = cvtpk(f2, f3);
    U.u[2] = cvtpk(f4, f5);
    U.u[3] = cvtpk(f6, f7);
    return U.v;
}

// ---------------- prep ----------------
// block 0: va1 + va2; block 1: W1b; block 2: W2b;
// blocks 3..3+NHIST: LDS-histogram degree count + rank capture (u8-packed).
// INVARIANT: EPB % 4 == 0 (int4 edge walk must not straddle partition bounds).
__global__ void prep_kernel(const float* __restrict__ W1,
                            const float* __restrict__ as1, const float* __restrict__ ad1,
                            const float* __restrict__ W2,
                            const float* __restrict__ as2, const float* __restrict__ ad2,
                            const int* __restrict__ ei,
                            unsigned short* __restrict__ va1h, unsigned short* __restrict__ va1l,
                            unsigned short* __restrict__ va2b,
                            unsigned short* __restrict__ W1b, unsigned short* __restrict__ W2b,
                            unsigned char* __restrict__ partial8,
                            unsigned char* __restrict__ rank8) {
    const int tid = threadIdx.x;
    const int b = blockIdx.x;
    if (b >= 3) {  // -------- histogram count + rank capture --------
        __shared__ unsigned lhist[LDSW];
        for (int i = tid; i < LDSW; i += 256) lhist[i] = 0;
        __syncthreads();
        const int hb = b - 3;
        const int* dp = ei + EE + hb * EPB;
        unsigned char* rk = rank8 + (size_t)hb * EPB;
        for (int e0 = tid * 4; e0 < EPB; e0 += 1024) {
            int4 d4 = *(const int4*)(dp + e0);
            uchar4 r;
            {
                const unsigned d = (unsigned)d4.x, sh8 = (d & 3) << 3;
                unsigned old = atomicAdd(&lhist[d >> 2], 1u << sh8);
                r.x = (unsigned char)((old >> sh8) & 0xff);
            }
            {
                const unsigned d = (unsigned)d4.y, sh8 = (d & 3) << 3;
                unsigned old = atomicAdd(&lhist[d >> 2], 1u << sh8);
                r.y = (unsigned char)((old >> sh8) & 0xff);
            }
            {
                const unsigned d = (unsigned)d4.z, sh8 = (d & 3) << 3;
                unsigned old = atomicAdd(&lhist[d >> 2], 1u << sh8);
                r.z = (unsigned char)((old >> sh8) & 0xff);
            }
            {
                const unsigned d = (unsigned)d4.w, sh8 = (d & 3) << 3;
                unsigned old = atomicAdd(&lhist[d >> 2], 1u << sh8);
                r.w = (unsigned char)((old >> sh8) & 0xff);
            }
            *(uchar4*)(rk + e0) = r;  // coalesced rank store
        }
        __syncthreads();
        unsigned* pb = (unsigned*)(partial8 + (size_t)hb * PADN);
        for (int i = tid; i < LDSW; i += 256) pb[i] = lhist[i];
        return;
    }
    if (b == 1) {  // W1b fragments: 2048 frags
        for (int f = tid; f < 2048; f += 256) {
            const int lane = f & 63, kc = (f >> 6) & 3, ntw = f >> 8;
            const int q = lane >> 4, c = lane & 15;
            const int col = ntw * 16 + c;
            const int k0 = kc * 32 + q * 8;
            const float* wp = W1 + (size_t)k0 * C1 + col;
            *(bf16x8*)(W1b + (size_t)f * 8) =
                pack8(wp[0], wp[C1], wp[2 * C1], wp[3 * C1],
                      wp[4 * C1], wp[5 * C1], wp[6 * C1], wp[7 * C1]);
        }
        return;
    }
    if (b == 2) {  // W2b fragments: 768 frags
        for (int f = tid; f < 768; f += 256) {
            const int lane = f & 63, kc = (f >> 6) & 3, nt = f >> 8;
            const int q = lane >> 4, c = lane & 15;
            const int col = nt * 16 + c;
            const int k0 = kc * 32 + q * 8;
            bf16x8 v = 0;
            if (col < CLASSES) {
                const float* wp = W2 + (size_t)k0 * CLASSES + col;
                v = pack8(wp[0], wp[CLASSES], wp[2 * CLASSES], wp[3 * CLASSES],
                          wp[4 * CLASSES], wp[5 * CLASSES], wp[6 * CLASSES], wp[7 * CLASSES]);
            }
            *(bf16x8*)(W2b + (size_t)f * 8) = v;
        }
        return;
    }
    {   // va1: thread (k, half) computes 4 heads x {src,dst}
        const int k = tid >> 1, half = tid & 1;
        const float* wrow = W1 + (size_t)k * C1 + half * 64;
        #pragma unroll
        for (int hh = 0; hh < 4; ++hh) {
            const int h = half * 4 + hh;
            float s = 0.f, d = 0.f;
            #pragma unroll
            for (int t = 0; t < 16; ++t) {
                float wv = wrow[hh * 16 + t];
                s += wv * as1[h * HID + t];
                d += wv * ad1[h * HID + t];
            }
            s *= LOG2E; d *= LOG2E;
            va1h[h * 128 + k]       = bf1(s);
            va1l[h * 128 + k]       = bf1(s - bf1f(s));
            va1h[(h + 8) * 128 + k] = bf1(d);
            va1l[(h + 8) * 128 + k] = bf1(d - bf1f(d));
        }
    }
    if (tid < C1) {  // va2
        const float* wrow = W2 + (size_t)tid * CLASSES;
        float s = 0.f, d = 0.f;
        #pragma unroll
        for (int c2 = 0; c2 < CLASSES; ++c2) {
            float wv = wrow[c2];
            s += wv * as2[c2];
            d += wv * ad2[c2];
        }
        s *= LOG2E; d *= LOG2E;
        va2b[0 * 128 + tid] = bf1(s);
        va2b[1 * 128 + tid] = bf1(s - bf1f(s));
        va2b[2 * 128 + tid] = bf1(d);
        va2b[3 * 128 + tid] = bf1(d - bf1f(d));
    }
}

// ---------------- scan1: deg + partial rowptr + per-partition prefixes ----------------
__global__ void scan1_kernel(const unsigned char* __restrict__ partial8,
                             unsigned char* __restrict__ pfx8,
                             int* __restrict__ deg,
                             int* __restrict__ rowptrA, int* __restrict__ bsum) {
    __shared__ int sh[256];
    const int tid = threadIdx.x;
    const int base = blockIdx.x * 1024 + tid * 4;  // < PADN always
    int t0 = 0, t1 = 0, t2 = 0, t3 = 0;
    #pragma unroll 8
    for (int b = 0; b < NHIST; ++b) {
        uchar4 pf;
        pf.x = (unsigned char)t0; pf.y = (unsigned char)t1;
        pf.z = (unsigned char)t2; pf.w = (unsigned char)t3;
        *(uchar4*)(pfx8 + (size_t)b * PADN + base) = pf;   // prefix BEFORE partition b
        uchar4 p = *(const uchar4*)(partial8 + (size_t)b * PADN + base);
        t0 += p.x; t1 += p.y; t2 += p.z; t3 += p.w;
    }
    int v[4], s[4];
    v[0] = (base + 0 < NN) ? t0 + 1 : 0;
    v[1] = (base + 1 < NN) ? t1 + 1 : 0;
    v[2] = (base + 2 < NN) ? t2 + 1 : 0;
    v[3] = (base + 3 < NN) ? t3 + 1 : 0;
    #pragma unroll
    for (int j = 0; j < 4; ++j)
        if (base + j < NN) deg[base + j] = v[j];  // total incl self-loop
    s[0] = v[0]; s[1] = s[0] + v[1]; s[2] = s[1] + v[2]; s[3] = s[2] + v[3];
    int T = s[3];
    sh[tid] = T;
    __syncthreads();
    for (int off = 1; off < 256; off <<= 1) {
        int xv = (tid >= off) ? sh[tid - off] : 0;
        __syncthreads();
        sh[tid] += xv;
        __syncthreads();
    }
    int excl = sh[tid] - T;
    #pragma unroll
    for (int j = 0; j < 4; ++j)
        if (base + j < NN) rowptrA[base + j] = excl + s[j] - v[j];
    if (tid == 255) bsum[blockIdx.x] = sh[255];
}

// ---------------- GEMM1 + elogit1 + fill + scan3, one launch ----------------
// bids [0, FILLB): fill (virtual rowptr = rowptrA + bsum-prefix; LDS-free, atomic-free)
// bids [FILLB, FILLB+S3B): finalize rowptrF + self-loop csr
// bids [FILLB+S3B, ...): gemm (wave-per-mtile)
__global__ __launch_bounds__(256, 4)
void gemm1_fill_kernel(const float* __restrict__ x,
                       const unsigned short* __restrict__ W1b,
                       const unsigned short* __restrict__ va1h,
                       const unsigned short* __restrict__ va1l,
                       const int* __restrict__ ei,
                       const int* __restrict__ rowptrA,
                       const int* __restrict__ bsum,
                       const unsigned char* __restrict__ pfx8,
                       const unsigned char* __restrict__ rank8,
                       int* __restrict__ rowptrF,
                       unsigned short* __restrict__ csr,
                       _Float16* __restrict__ h1h,
                       float* __restrict__ e_src, float* __restrict__ e_dst) {
    const int bid = blockIdx.x;
    const int tid = threadIdx.x;
    if (bid < FILLB + S3B) {
        __shared__ int ex[64];  // chunk-offset prefix (49 chunks)
        if (tid < 64) {
            int v = (tid < NCHUNKS) ? bsum[tid] : 0;
            int s = v;
            #pragma unroll
            for (int off = 1; off < 64; off <<= 1) {
                int xv = __shfl_up(s, off);
                if (tid >= off) s += xv;
            }
            ex[tid] = s - v;  // exclusive prefix
        }
        __syncthreads();
        if (bid < FILLB) {  // -------- fill: arithmetic scatter --------
            const int part = bid / FSUB;
            const int chunkoff = (bid % FSUB) * FPB;
            const int gbase = part * EPB + chunkoff;
            const int* sp = ei + gbase;
            const int* dp = ei + EE + gbase;
            const unsigned char* pf = pfx8 + (size_t)part * PADN;
            const unsigned char* rk = rank8 + (size_t)part * EPB + chunkoff;
            for (int e0 = tid * 4; e0 < FPB; e0 += 1024) {
                int4 s4 = *(const int4*)(sp + e0);
                int4 d4 = *(const int4*)(dp + e0);
                uchar4 r = *(const uchar4*)(rk + e0);
                csr[rowptrA[d4.x] + ex[d4.x >> 10] + 1 + pf[d4.x] + r.x] = (unsigned short)s4.x;
                csr[rowptrA[d4.y] + ex[d4.y >> 10] + 1 + pf[d4.y] + r.y] = (unsigned short)s4.y;
                csr[rowptrA[d4.z] + ex[d4.z >> 10] + 1 + pf[d4.z] + r.z] = (unsigned short)s4.z;
                csr[rowptrA[d4.w] + ex[d4.w >> 10] + 1 + pf[d4.w] + r.w] = (unsigned short)s4.w;
            }
        } else {  // -------- scan3 role: finalize rowptrF + self-loop --------
            int i = (bid - FILLB) * 256 + tid;
            if (i < NN) {
                int rp = rowptrA[i] + ex[i >> 10];
                rowptrF[i] = rp;
                csr[rp] = (unsigned short)i;  // self-loop first
            }
        }
        return;
    }
    const int gemmb = bid - FILLB - S3B;
    const int w = tid >> 6, lane = tid & 63;
    const int q = lane >> 4, c = lane & 15;
    const int m0 = (gemmb * 4 + w) * 16;

    int row = m0 + c;
    if (row > NN - 1) row = NN - 1;
    bf16x8 afrag[4];
    #pragma unroll
    for (int kc = 0; kc < 4; ++kc) {
        const float* xp = x + (size_t)row * F_IN + kc * 32 + q * 8;
        float4 p0 = *(const float4*)xp;
        float4 p1 = *(const float4*)(xp + 4);
        afrag[kc] = pack8(p0.x, p0.y, p0.z, p0.w, p1.x, p1.y, p1.z, p1.w);
    }

    // e-MFMA (fused elogit1)
    {
        f32x4 acce = {0.f, 0.f, 0.f, 0.f};
        #pragma unroll
        for (int kc = 0; kc < 4; ++kc) {
            const int coloff = kc * 32 + q * 8;
            bf16x8 beh = *(const bf16x8*)(va1h + c * 128 + coloff);
            bf16x8 bel = *(const bf16x8*)(va1l + c * 128 + coloff);
            acce = __builtin_amdgcn_mfma_f32_16x16x32_bf16(afrag[kc], beh, acce, 0, 0, 0);
            acce = __builtin_amdgcn_mfma_f32_16x16x32_bf16(afrag[kc], bel, acce, 0, 0, 0);
        }
        float* ep = (c < 8) ? e_src : e_dst;
        const int cc = c & 7;
        #pragma unroll
        for (int r = 0; r < 4; ++r) {
            const int ro = m0 + q * 4 + r;
            if (ro < NN) ep[(size_t)ro * HEADS + cc] = acce[r];
        }
    }

    // main GEMM: 8 n-tiles
    #pragma unroll 2
    for (int nt = 0; nt < 8; ++nt) {
        bf16x8 bf0 = *(const bf16x8*)(W1b + (size_t)((nt * 4 + 0) * 64 + lane) * 8);
        bf16x8 bf1_ = *(const bf16x8*)(W1b + (size_t)((nt * 4 + 1) * 64 + lane) * 8);
        bf16x8 bf2 = *(const bf16x8*)(W1b + (size_t)((nt * 4 + 2) * 64 + lane) * 8);
        bf16x8 bf3 = *(const bf16x8*)(W1b + (size_t)((nt * 4 + 3) * 64 + lane) * 8);
        f32x4 a = {0.f, 0.f, 0.f, 0.f};
        a = __builtin_amdgcn_mfma_f32_16x16x32_bf16(afrag[0], bf0, a, 0, 0, 0);
        a = __builtin_amdgcn_mfma_f32_16x16x32_bf16(afrag[1], bf1_, a, 0, 0, 0);
        a = __builtin_amdgcn_mfma_f32_16x16x32_bf16(afrag[2], bf2, a, 0, 0, 0);
        a = __builtin_amdgcn_mfma_f32_16x16x32_bf16(afrag[3], bf3, a, 0, 0, 0);
        #pragma unroll
        for (int r = 0; r < 4; ++r) {
            const int ro = m0 + q * 4 + r;
            if (ro < NN) h1h[(size_t)ro * C1 + nt * 16 + c] = (_Float16)a[r];
        }
    }
}

// ---------------- layer-1 agg (2 dst/group, 16-deep gather pipeline) + GEMM2 ----------
// block = 256 = 16 groups; group owns dsts d0=b*32+grp and d1=d0+16.
// Agg results staged in LDS [32][132]; waves 0,1 each run a 16-row gemm2 m-tile.
__global__ __launch_bounds__(256)
void agg1_gemm2_kernel(const _Float16* __restrict__ h1h,
                       const float* __restrict__ e_src, const float* __restrict__ e_dst,
                       const int* __restrict__ rowptr, const int* __restrict__ deg,
                       const unsigned short* __restrict__ csr,
                       const float* __restrict__ b1,
                       const unsigned short* __restrict__ W2b,
                       const unsigned short* __restrict__ va2b,
                       _Float16* __restrict__ h2h,
                       float* __restrict__ e_src2, float* __restrict__ e_dst2) {
    __shared__ unsigned short hm[32][132];  // bf16 m-tiles, +4 pad
    const int tid = threadIdx.x;
    const int grp = tid >> 4;                   // 0..15
    const int l = tid & 15;                     // channels 8l..8l+7
    const int hd = l >> 1;
    const int d0 = blockIdx.x * 32 + grp;
    const int d1t = d0 + 16;
    const bool live1 = d1t < NN;
    const int d1 = live1 ? d1t : d0;
    const float ed0 = e_dst[(size_t)d0 * HEADS + hd];
    const float ed1 = e_dst[(size_t)d1 * HEADS + hd];
    const int st0 = rowptr[d0], st1 = rowptr[d1];
    const int c0 = deg[d0], c1 = deg[d1];
    const int cmax = (c0 > c1) ? c0 : c1;

    float den0 = 0.f, den1 = 0.f;
    float a0[8] = {0.f, 0.f, 0.f, 0.f, 0.f, 0.f, 0.f, 0.f};
    float a1[8] = {0.f, 0.f, 0.f, 0.f, 0.f, 0.f, 0.f, 0.f};

    for (int i = 0; i < cmax; i += 8) {
        int s0[8], s1[8];
        #pragma unroll
        for (int e = 0; e < 8; ++e) {
            s0[e] = csr[st0 + ((i + e < c0) ? i + e : c0 - 1)];
            s1[e] = csr[st1 + ((i + e < c1) ? i + e : c1 - 1)];
        }
        float es0[8], es1[8];
        #pragma unroll
        for (int e = 0; e < 8; ++e) {
            es0[e] = e_src[(size_t)s0[e] * HEADS + hd];
            es1[e] = e_src[(size_t)s1[e] * HEADS + hd];
        }
        h16x8 g0[8], g1[8];
        #pragma unroll
        for (int e = 0; e < 8; ++e) {
            g0[e] = *(const h16x8*)(h1h + (size_t)s0[e] * C1 + 8 * l);
            g1[e] = *(const h16x8*)(h1h + (size_t)s1[e] * C1 + 8 * l);
        }
        float w0[8], w1[8];
        #pragma unroll
        for (int e = 0; e < 8; ++e) {
            float t0 = fexp2(lrelu(es0[e] + ed0));
            float t1 = fexp2(lrelu(es1[e] + ed1));
            w0[e] = (i + e < c0) ? t0 : 0.f;
            w1[e] = (i + e < c1) ? t1 : 0.f;
            den0 += w0[e];
            den1 += w1[e];
        }
        #pragma unroll
        for (int e = 0; e < 8; ++e) {
            #pragma unroll
            for (int j = 0; j < 8; ++j) {  // v_fma_mix_f32
                a0[j] = fmaf((float)g0[e][j], w0[e], a0[j]);
                a1[j] = fmaf((float)g1[e][j], w1[e], a1[j]);
            }
        }
    }
    {
        const float inv = 1.f / (den0 + 1e-16f);
        float o[8];
        #pragma unroll
        for (int k = 0; k < 8; ++k) {
            float t = a0[k] * inv + b1[8 * l + k];
            o[k] = (t > 0.f) ? t : fexp2(t * LOG2E) - 1.f;
        }
        uint4 st;
        st.x = cvtpk(o[0], o[1]); st.y = cvtpk(o[2], o[3]);
        st.z = cvtpk(o[4], o[5]); st.w = cvtpk(o[6], o[7]);
        *(uint4*)(&hm[grp][8 * l]) = st;
    }
    {
        const float inv = 1.f / (den1 + 1e-16f);
        float o[8];
        #pragma unroll
        for (int k = 0; k < 8; ++k) {
            float t = a1[k] * inv + b1[8 * l + k];
            o[k] = (t > 0.f) ? t : fexp2(t * LOG2E) - 1.f;
        }
        uint4 st;
        st.x = cvtpk(o[0], o[1]); st.y = cvtpk(o[2], o[3]);
        st.z = cvtpk(o[4], o[5]); st.w = cvtpk(o[6], o[7]);
        *(uint4*)(&hm[grp + 16][8 * l]) = st;  // dup of d0 if !live1; stores guarded below
    }
    __syncthreads();

    // -------- GEMM2 + elogit2: waves 0,1 each handle a 16-row m-tile --------
    if (tid < 128) {
        const int wv = tid >> 6;
        const int lane = tid & 63, q = lane >> 4, c = lane & 15;
        const int m0 = blockIdx.x * 32 + wv * 16;
        bf16x8 afrag[4];
        #pragma unroll
        for (int kc = 0; kc < 4; ++kc)
            afrag[kc] = *(const bf16x8*)(&hm[wv * 16 + c][kc * 32 + q * 8]);

        bf16x8 bfrag[3][4];
        #pragma unroll
        for (int nt = 0; nt < 3; ++nt)
            #pragma unroll
            for (int kc = 0; kc < 4; ++kc)
                bfrag[nt][kc] = *(const bf16x8*)(W2b + (size_t)((nt * 4 + kc) * 64 + lane) * 8);
        bf16x8 bfe[4];
        #pragma unroll
        for (int kc = 0; kc < 4; ++kc) {
            bf16x8 bb = 0;
            if (c < 4) bb = *(const bf16x8*)(va2b + c * 128 + kc * 32 + q * 8);
            bfe[kc] = bb;
        }

        f32x4 a2[3] = {{0.f,0.f,0.f,0.f},{0.f,0.f,0.f,0.f},{0.f,0.f,0.f,0.f}};
        f32x4 acce = {0.f, 0.f, 0.f, 0.f};
        #pragma unroll
        for (int kc = 0; kc < 4; ++kc) {
            a2[0] = __builtin_amdgcn_mfma_f32_16x16x32_bf16(afrag[kc], bfrag[0][kc], a2[0], 0, 0, 0);
            a2[1] = __builtin_amdgcn_mfma_f32_16x16x32_bf16(afrag[kc], bfrag[1][kc], a2[1], 0, 0, 0);
            a2[2] = __builtin_amdgcn_mfma_f32_16x16x32_bf16(afrag[kc], bfrag[2][kc], a2[2], 0, 0, 0);
            acce  = __builtin_amdgcn_mfma_f32_16x16x32_bf16(afrag[kc], bfe[kc],      acce,  0, 0, 0);
        }
        #pragma unroll
        for (int r = 0; r < 4; ++r) {
            const int ro = m0 + q * 4 + r;
            float v = acce[r] + __shfl_xor(acce[r], 1);
            if (ro < NN) {
                #pragma unroll
                for (int nt = 0; nt < 3; ++nt) {
                    const int col = nt * 16 + c;
                    if (col < CLASSES)
                        h2h[(size_t)ro * CLASSES + col] = (_Float16)a2[nt][r];
                }
                if (c == 0) e_src2[ro] = v;
                if (c == 2) e_dst2[ro] = v;
            }
        }
    }
}

// ---------------- layer-2 aggregation: dst-per-group, 8-edge pipeline ----------------
__global__ __launch_bounds__(64)
void agg2_kernel(const _Float16* __restrict__ h2h,
                 const float* __restrict__ e_src, const float* __restrict__ e_dst,
                 const int* __restrict__ rowptr, const int* __restrict__ deg,
                 const unsigned short* __restrict__ csr,
                 const float* __restrict__ b2, float* __restrict__ out) {
    const int tid = threadIdx.x;
    const int eg = tid / 20;      // 0..2 active groups, 3 = idle
    const int c  = tid % 20;
    const int d = blockIdx.x * 3 + eg;
    const bool live = (eg < 3) && (d < NN);
    const int dcl = live ? d : 0;
    const float ed = e_dst[dcl];
    const int start = rowptr[dcl];
    const int cnt = live ? deg[dcl] : 0;

    float denom = 0.f, acc0 = 0.f, acc1 = 0.f;
    for (int i = 0; i < cnt; i += 8) {
        int s[8];
        #pragma unroll
        for (int e = 0; e < 8; ++e)
            s[e] = csr[start + ((i + e < cnt) ? i + e : i)];
        float es[8];
        #pragma unroll
        for (int e = 0; e < 8; ++e)
            es[e] = e_src[s[e]];
        h16x2 g[8];
        #pragma unroll
        for (int e = 0; e < 8; ++e)
            g[e] = *(const h16x2*)(h2h + (size_t)s[e] * CLASSES + 2 * c);
        float w[8];
        #pragma unroll
        for (int e = 0; e < 8; ++e) {
            float we = fexp2(lrelu(es[e] + ed));
            w[e] = (i + e < cnt) ? we : 0.f;
            denom += w[e];
        }
        #pragma unroll
        for (int e = 0; e < 8; ++e) {
            acc0 = fmaf((float)g[e][0], w[e], acc0);
            acc1 = fmaf((float)g[e][1], w[e], acc1);
        }
    }
    if (live) {
        const float inv = 1.f / (denom + 1e-16f);
        float2 o;
        o.x = acc0 * inv + b2[2 * c];
        o.y = acc1 * inv + b2[2 * c + 1];
        *(float2*)(out + (size_t)d * CLASSES + 2 * c) = o;
    }
}

extern "C" void kernel_launch(void* const* d_in, const int* in_sizes, int n_in,
                              void* d_out, int out_size, void* d_ws, size_t ws_size,
                              hipStream_t stream) {
    const float* x      = (const float*)d_in[0];
    const int*   ei     = (const int*)d_in[1];
    const float* W1     = (const float*)d_in[2];
    const float* a_src1 = (const float*)d_in[3];
    const float* a_dst1 = (const float*)d_in[4];
    const float* b1     = (const float*)d_in[5];
    const float* W2     = (const float*)d_in[6];
    const float* a_src2 = (const float*)d_in[7];
    const float* a_dst2 = (const float*)d_in[8];
    const float* b2     = (const float*)d_in[9];
    float* out = (float*)d_out;

    char* ws = (char*)d_ws;
    size_t off = 0;
    auto alloc = [&](size_t bytes) { char* p = ws + off; off += (bytes + 255) & ~(size_t)255; return p; };
    _Float16* h1h = (_Float16*)alloc((size_t)NN * C1 * 2);
    _Float16* h2h = (_Float16*)alloc((size_t)NN * CLASSES * 2);
    float* e_src1 = (float*)alloc((size_t)NN * HEADS * 4);
    float* e_dst1 = (float*)alloc((size_t)NN * HEADS * 4);
    float* e_src2 = (float*)alloc((size_t)NN * 4);
    float* e_dst2 = (float*)alloc((size_t)NN * 4);
    int*   deg     = (int*)alloc((size_t)NN * 4);
    int*   rowptrA = (int*)alloc((size_t)NN * 4);
    int*   rowptrF = (int*)alloc((size_t)NN * 4);
    unsigned short* csr  = (unsigned short*)alloc((size_t)ET * 2);
    int*   bsum   = (int*)alloc(256 * 4);
    unsigned short* va1h = (unsigned short*)alloc(16 * 128 * 2);
    unsigned short* va1l = (unsigned short*)alloc(16 * 128 * 2);
    unsigned short* va2b = (unsigned short*)alloc(4 * 128 * 2);
    unsigned short* W1b  = (unsigned short*)alloc(2048 * 8 * 2);
    unsigned short* W2b  = (unsigned short*)alloc(768 * 8 * 2);
    unsigned char* partial8 = (unsigned char*)alloc((size_t)NHIST * PADN);
    unsigned char* pfx8     = (unsigned char*)alloc((size_t)NHIST * PADN);
    unsigned char* rank8    = (unsigned char*)alloc((size_t)EE);

    prep_kernel<<<3 + NHIST, 256, 0, stream>>>(W1, a_src1, a_dst1, W2, a_src2, a_dst2, ei,
                                               va1h, va1l, va2b, W1b, W2b, partial8, rank8);
    scan1_kernel<<<NCHUNKS, 256, 0, stream>>>(partial8, pfx8, deg, rowptrA, bsum);
    gemm1_fill_kernel<<<FILLB + S3B + GB, 256, 0, stream>>>(x, W1b, va1h, va1l, ei,
                                                            rowptrA, bsum, pfx8, rank8,
                                                            rowptrF, csr, h1h, e_src1, e_dst1);

    agg1_gemm2_kernel<<<(NN + 31) / 32, 256, 0, stream>>>(h1h, e_src1, e_dst1, rowptrF, deg,
                                                          csr, b1, W2b, va2b,
                                                          h2h, e_src2, e_dst2);

    agg2_kernel<<<(NN + 2) / 3, 64, 0, stream>>>(h2h, e_src2, e_dst2, rowptrF, deg, csr, b2, out);
}